// Round 11
// baseline (271.476 us; speedup 1.0000x reference)
//
#include <hip/hip_runtime.h>
#include <hip/hip_bf16.h>

#define BDIM 2
#define SDIM 2048
#define HDIM 8
#define DK 32
#define DMODEL 256
#define SCALE_Q 0.17677669529663687f  // 1/sqrt(32)

typedef __attribute__((ext_vector_type(8))) short bf16x8;
typedef __attribute__((ext_vector_type(4))) float f32x4;

__device__ __forceinline__ unsigned short f2bf(float f) {
    union { float f; unsigned int i; } c;
    c.f = f;
    unsigned int u = c.i;
    return (unsigned short)((u + 0x7FFFu + ((u >> 16) & 1u)) >> 16);
}

// ---------------------------------------------------------------------------
// Kernel 1: fused QKV projections from FLOAT32 inputs. y = x @ W^T + b.
// Q written pre-scaled by 1/sqrt(Dk), layout [B,H,S,Dk] bf16.
// K layout [B,H,S,Dk] bf16. V written TRANSPOSED: [B,H,Dk,S] bf16 so the
// PV MFMA B-fragment (8 consecutive keys at fixed d) is one 16B load.
// ---------------------------------------------------------------------------
__global__ __launch_bounds__(256) void proj_kernel(
    const float* __restrict__ query,
    const float* __restrict__ key,
    const float* __restrict__ value,
    const float* __restrict__ Wq, const float* __restrict__ bq,
    const float* __restrict__ Wk, const float* __restrict__ bk,
    const float* __restrict__ Wv, const float* __restrict__ bv,
    unsigned short* __restrict__ qws,
    unsigned short* __restrict__ kws,
    unsigned short* __restrict__ vtws)
{
    __shared__ float xl[16][DMODEL];   // 16 tokens x 256 feats, f32

    const int m = blockIdx.y;          // 0=Q, 1=K, 2=V
    const float* x    = (m == 0) ? query : (m == 1) ? key : value;
    const float* W    = (m == 0) ? Wq : (m == 1) ? Wk : Wv;
    const float* bias = (m == 0) ? bq : (m == 1) ? bk : bv;

    const int t0  = blockIdx.x * 16;   // first token of this tile
    const int tid = threadIdx.x;

    // stage X tile (4096 f32) into LDS, float4-vectorized
    {
        const float* xp = x + t0 * DMODEL;
        #pragma unroll
        for (int c = 0; c < 4; ++c) {
            int idx = (tid + c * 256) * 4;       // float index, 16B aligned
            float4 v4 = *(const float4*)(xp + idx);
            int t = idx >> 8, i = idx & 255;
            *(float4*)&xl[t][i] = v4;
        }
    }
    __syncthreads();

    const int o = tid;                 // output feature this thread owns
    float acc[16];
    #pragma unroll
    for (int t = 0; t < 16; ++t) acc[t] = 0.f;

    const float* wrow = W + o * DMODEL;
    for (int i = 0; i < DMODEL; i += 8) {
        float4 w0 = *(const float4*)(wrow + i);
        float4 w1 = *(const float4*)(wrow + i + 4);
        #pragma unroll
        for (int t = 0; t < 16; ++t) {
            float4 a = *(const float4*)&xl[t][i];
            float4 bb = *(const float4*)&xl[t][i + 4];
            acc[t] += a.x * w0.x + a.y * w0.y + a.z * w0.z + a.w * w0.w
                    + bb.x * w1.x + bb.y * w1.y + bb.z * w1.z + bb.w * w1.w;
        }
    }

    const float bo = bias[o];
    const int h = o >> 5, dk = o & 31;
    #pragma unroll
    for (int t = 0; t < 16; ++t) {
        int tok = t0 + t;
        int b = tok >> 11, s = tok & 2047;
        float v = acc[t] + bo;
        if (m == 0) {
            qws[(((b * HDIM + h) * SDIM + s) << 5) + dk] = f2bf(v * SCALE_Q);
        } else if (m == 1) {
            kws[(((b * HDIM + h) * SDIM + s) << 5) + dk] = f2bf(v);
        } else {
            vtws[(((b * HDIM + h) * DK + dk) << 11) + s] = f2bf(v);
        }
    }
}

// ---------------------------------------------------------------------------
// Kernel 2: per (b, h, 16-row stripe): scores via MFMA -> LDS f32 ->
// per-wave register-resident Michelot sparsemax -> P bf16 back to LDS
// (overlapping the dead score buffer, barrier-protected) -> PV via MFMA
// with per-wave key partials reduced through LDS.
// OUTPUT IS FLOAT32 (reference output dtype).
// Dynamic LDS: 128KB scores / 64KB P + 32KB partials (time-shared).
// ---------------------------------------------------------------------------
#define PSTR 2056            // P row stride in bf16 elements (2048 + 8 pad)
#define PART_OFF 66560       // byte offset of partials region (>= 16*PSTR*2)

__global__ __launch_bounds__(1024) void attn_kernel(
    const unsigned short* __restrict__ qws,
    const unsigned short* __restrict__ kws,
    const unsigned short* __restrict__ vtws,
    float* __restrict__ out)
{
    extern __shared__ char smem[];
    float* sc = (float*)smem;                      // [16][2048] f32 scores
    unsigned short* pl = (unsigned short*)smem;    // [16][PSTR] bf16 P (overlaps sc)
    float* part = (float*)(smem + PART_OFF);       // [16 waves][512] f32 partials

    const int i0 = blockIdx.x * 16;
    const int h  = blockIdx.y;
    const int b  = blockIdx.z;
    const int tid = threadIdx.x;
    const int w = tid >> 6, l = tid & 63;
    const int lr = l & 15, lk = l >> 4;            // fragment row/col, k-block

    const unsigned short* qp = qws + ((b * HDIM + h) * SDIM) * DK;
    const unsigned short* kp = kws + ((b * HDIM + h) * SDIM) * DK;
    const unsigned short* vp = vtws + ((b * HDIM + h) * DK) * SDIM;

    // ---- Phase 1: scores.  Wave w computes keys [w*128, (w+1)*128). ----
    {
        bf16x8 af = *(const bf16x8*)(qp + (i0 + lr) * DK + lk * 8);
        f32x4 dzero = {0.f, 0.f, 0.f, 0.f};
        #pragma unroll
        for (int t = 0; t < 8; ++t) {
            int j0 = w * 128 + t * 16;
            bf16x8 bfr = *(const bf16x8*)(kp + (j0 + lr) * DK + lk * 8);
            f32x4 d = __builtin_amdgcn_mfma_f32_16x16x32_bf16(af, bfr, dzero, 0, 0, 0);
            #pragma unroll
            for (int q = 0; q < 4; ++q)
                sc[(lk * 4 + q) * SDIM + j0 + lr] = d[q];
        }
    }
    __syncthreads();

    // ---- Phase 2: sparsemax, wave w owns row w. z in registers. ----
    float z[32];
    #pragma unroll
    for (int u = 0; u < 16; ++u) {
        float2 v2 = *(const float2*)&sc[w * SDIM + 2 * l + 128 * u];
        z[2 * u] = v2.x;
        z[2 * u + 1] = v2.y;
    }
    __syncthreads();   // all score reads done -> sc region reusable for P

    float tau = -1e30f;
    float cnt = -1.f;
    for (int it = 0; it < 64; ++it) {
        float ps = 0.f, pc = 0.f;
        #pragma unroll
        for (int e = 0; e < 32; ++e) {
            if (z[e] > tau) { ps += z[e]; pc += 1.f; }
        }
        #pragma unroll
        for (int mk = 1; mk < 64; mk <<= 1) {
            ps += __shfl_xor(ps, mk, 64);
            pc += __shfl_xor(pc, mk, 64);
        }
        float ntau = (ps - 1.f) / pc;   // pc >= 1 always (max stays active)
        if (pc == cnt) { tau = ntau; break; }
        cnt = pc;
        tau = ntau;
    }

    // P = max(z - tau, 0) -> bf16 pairs into pl[w][j], j = 2l + 128u {+1}
    #pragma unroll
    for (int u = 0; u < 16; ++u) {
        float p0 = z[2 * u] - tau;     p0 = p0 > 0.f ? p0 : 0.f;
        float p1 = z[2 * u + 1] - tau; p1 = p1 > 0.f ? p1 : 0.f;
        unsigned int packed = (unsigned int)f2bf(p0) | ((unsigned int)f2bf(p1) << 16);
        *(unsigned int*)&pl[w * PSTR + 2 * l + 128 * u] = packed;
    }
    __syncthreads();

    // ---- Phase 3: PV partials over this wave's keys [w*128, w*128+128) ----
    f32x4 acc0 = {0.f, 0.f, 0.f, 0.f};
    f32x4 acc1 = {0.f, 0.f, 0.f, 0.f};
    #pragma unroll
    for (int ks = 0; ks < 4; ++ks) {
        int kk = w * 128 + ks * 32;
        bf16x8 paf = *(const bf16x8*)&pl[lr * PSTR + kk + lk * 8];
        bf16x8 v0 = *(const bf16x8*)(vp + lr * SDIM + kk + lk * 8);
        bf16x8 v1 = *(const bf16x8*)(vp + (16 + lr) * SDIM + kk + lk * 8);
        acc0 = __builtin_amdgcn_mfma_f32_16x16x32_bf16(paf, v0, acc0, 0, 0, 0);
        acc1 = __builtin_amdgcn_mfma_f32_16x16x32_bf16(paf, v1, acc1, 0, 0, 0);
    }
    #pragma unroll
    for (int q = 0; q < 4; ++q) {
        part[w * 512 + (lk * 4 + q) * 32 + lr]      = acc0[q];
        part[w * 512 + (lk * 4 + q) * 32 + 16 + lr] = acc1[q];
    }
    __syncthreads();

    // ---- Phase 4: reduce the 16 wave-partials, write row w of output (f32) ----
    {
        int d = l & 31, half = l >> 5;
        float s = 0.f;
        #pragma unroll
        for (int p = 0; p < 8; ++p)
            s += part[(half * 8 + p) * 512 + w * 32 + d];
        s += __shfl_xor(s, 32, 64);
        if (l < 32)
            out[(b * SDIM + i0 + w) * DMODEL + h * DK + d] = s;
    }
}

extern "C" void kernel_launch(void* const* d_in, const int* in_sizes, int n_in,
                              void* d_out, int out_size, void* d_ws, size_t ws_size,
                              hipStream_t stream) {
    const float* query = (const float*)d_in[0];
    const float* key   = (const float*)d_in[1];
    const float* value = (const float*)d_in[2];
    const float* Wq = (const float*)d_in[3];
    const float* bq = (const float*)d_in[4];
    const float* Wk = (const float*)d_in[5];
    const float* bk = (const float*)d_in[6];
    const float* Wv = (const float*)d_in[7];
    const float* bv = (const float*)d_in[8];

    const int per = BDIM * HDIM * SDIM * DK;       // 1,048,576 elems
    unsigned short* qws  = (unsigned short*)d_ws;
    unsigned short* kws  = qws + per;
    unsigned short* vtws = kws + per;

    proj_kernel<<<dim3(BDIM * SDIM / 16, 3), 256, 0, stream>>>(
        query, key, value, Wq, bq, Wk, bk, Wv, bv, qws, kws, vtws);

    (void)hipFuncSetAttribute((const void*)attn_kernel,
                              hipFuncAttributeMaxDynamicSharedMemorySize, 131072);
    attn_kernel<<<dim3(SDIM / 16, HDIM, BDIM), 1024, 131072, stream>>>(
        qws, kws, vtws, (float*)d_out);
}

// Round 12
// 218.097 us; speedup vs baseline: 1.2448x; 1.2448x over previous
//
#include <hip/hip_runtime.h>
#include <hip/hip_bf16.h>

#define BDIM 2
#define SDIM 2048
#define HDIM 8
#define DK 32
#define DMODEL 256
#define SCALE_Q 0.17677669529663687f  // 1/sqrt(32)

typedef __attribute__((ext_vector_type(8))) short bf16x8;
typedef __attribute__((ext_vector_type(4))) float f32x4;

__device__ __forceinline__ float bf2f(unsigned short u) {
    union { unsigned int i; float f; } c;
    c.i = ((unsigned int)u) << 16;
    return c.f;
}
__device__ __forceinline__ unsigned short f2bf(float f) {
    union { float f; unsigned int i; } c;
    c.f = f;
    unsigned int u = c.i;
    return (unsigned short)((u + 0x7FFFu + ((u >> 16) & 1u)) >> 16);
}

// ---------------------------------------------------------------------------
// Kernel 0: split W (f32) -> Whi + Wlo bf16 pairs. 3 x 256x256 mats.
// ---------------------------------------------------------------------------
__global__ __launch_bounds__(256) void convw_kernel(
    const float* __restrict__ Wq, const float* __restrict__ Wk,
    const float* __restrict__ Wv,
    unsigned short* __restrict__ whi, unsigned short* __restrict__ wlo)
{
    const int m = blockIdx.y;
    const float* W = (m == 0) ? Wq : (m == 1) ? Wk : Wv;
    const int i = blockIdx.x * 2048 + threadIdx.x * 8;
    float4 a = *(const float4*)(W + i);
    float4 b = *(const float4*)(W + i + 4);
    float v[8] = {a.x, a.y, a.z, a.w, b.x, b.y, b.z, b.w};
    bf16x8 h8, l8;
    #pragma unroll
    for (int e = 0; e < 8; ++e) {
        unsigned short h = f2bf(v[e]);
        h8[e] = (short)h;
        l8[e] = (short)f2bf(v[e] - bf2f(h));
    }
    *(bf16x8*)(whi + m * 65536 + i) = h8;
    *(bf16x8*)(wlo + m * 65536 + i) = l8;
}

// ---------------------------------------------------------------------------
// Kernel 1: MFMA projections with split-bf16 (err ~2^-17, ~= f32 accuracy).
// y = Whi*Xhi + Whi*Xlo + Wlo*Xhi  (lo*lo dropped).
// Fragment mapping identical to attn phase-1 (verified): A=W rows->C rows,
// B=X rows->C cols:  D[o0+lk*4+q][t0+lr].
// Q pre-scaled; K row-major [B,H,S,Dk]; V transposed [B,H,Dk,S]. All bf16.
// ---------------------------------------------------------------------------
__global__ __launch_bounds__(256) void projmm_kernel(
    const float* __restrict__ query, const float* __restrict__ key,
    const float* __restrict__ value,
    const float* __restrict__ bq, const float* __restrict__ bk,
    const float* __restrict__ bv,
    const unsigned short* __restrict__ whi, const unsigned short* __restrict__ wlo,
    unsigned short* __restrict__ qws, unsigned short* __restrict__ kws,
    unsigned short* __restrict__ vtws)
{
    const int m = blockIdx.y;
    const float* x    = (m == 0) ? query : (m == 1) ? key : value;
    const float* bias = (m == 0) ? bq : (m == 1) ? bk : bv;
    const unsigned short* wh = whi + m * 65536;
    const unsigned short* wl = wlo + m * 65536;

    const int t0 = blockIdx.x * 16;
    const int tid = threadIdx.x;
    const int w = tid >> 6, l = tid & 63;
    const int lr = l & 15, lk = l >> 4;
    const int o0 = w * 64;

    f32x4 acc[4];
    #pragma unroll
    for (int nt = 0; nt < 4; ++nt) acc[nt] = (f32x4){0.f, 0.f, 0.f, 0.f};

    const float* xrow = x + (t0 + lr) * DMODEL;
    #pragma unroll
    for (int c = 0; c < 8; ++c) {
        const int kk = c * 32 + lk * 8;
        float4 xa = *(const float4*)(xrow + kk);
        float4 xb = *(const float4*)(xrow + kk + 4);
        float xv[8] = {xa.x, xa.y, xa.z, xa.w, xb.x, xb.y, xb.z, xb.w};
        bf16x8 xhi, xlo;
        #pragma unroll
        for (int e = 0; e < 8; ++e) {
            unsigned short h = f2bf(xv[e]);
            xhi[e] = (short)h;
            xlo[e] = (short)f2bf(xv[e] - bf2f(h));
        }
        #pragma unroll
        for (int nt = 0; nt < 4; ++nt) {
            const unsigned short* wb = wh + (o0 + nt * 16 + lr) * DMODEL + kk;
            const unsigned short* wc = wl + (o0 + nt * 16 + lr) * DMODEL + kk;
            bf16x8 ahi = *(const bf16x8*)wb;
            bf16x8 alo = *(const bf16x8*)wc;
            acc[nt] = __builtin_amdgcn_mfma_f32_16x16x32_bf16(ahi, xhi, acc[nt], 0, 0, 0);
            acc[nt] = __builtin_amdgcn_mfma_f32_16x16x32_bf16(ahi, xlo, acc[nt], 0, 0, 0);
            acc[nt] = __builtin_amdgcn_mfma_f32_16x16x32_bf16(alo, xhi, acc[nt], 0, 0, 0);
        }
    }

    const int token = t0 + lr;
    const int b = token >> 11, s = token & 2047;
    #pragma unroll
    for (int nt = 0; nt < 4; ++nt) {
        #pragma unroll
        for (int q = 0; q < 4; ++q) {
            const int o = o0 + nt * 16 + lk * 4 + q;
            const float y = acc[nt][q] + bias[o];
            const int h = o >> 5, dk = o & 31;
            if (m == 0)
                qws[(((b * HDIM + h) * SDIM + s) << 5) + dk] = f2bf(y * SCALE_Q);
            else if (m == 1)
                kws[(((b * HDIM + h) * SDIM + s) << 5) + dk] = f2bf(y);
            else
                vtws[(((b * HDIM + h) * DK + dk) << 11) + s] = f2bf(y);
        }
    }
}

// ---------------------------------------------------------------------------
// Kernel 2: per (b, h, 16-row stripe): scores via MFMA -> LDS f32 ->
// per-wave register-resident Michelot sparsemax (warm-started at rowmax-1,
// since tau >= max-1 always) -> P bf16 back to LDS -> PV via MFMA ->
// per-wave key-partials reduced through LDS. OUTPUT FLOAT32.
// Dynamic LDS: 128KB scores / 64KB P + 32KB partials (time-shared).
// ---------------------------------------------------------------------------
#define PSTR 2056            // P row stride in bf16 elements (2048 + 8 pad)
#define PART_OFF 66560       // byte offset of partials region (>= 16*PSTR*2)

__global__ __launch_bounds__(1024) void attn_kernel(
    const unsigned short* __restrict__ qws,
    const unsigned short* __restrict__ kws,
    const unsigned short* __restrict__ vtws,
    float* __restrict__ out)
{
    extern __shared__ char smem[];
    float* sc = (float*)smem;                      // [16][2048] f32 scores
    unsigned short* pl = (unsigned short*)smem;    // [16][PSTR] bf16 P (overlaps sc)
    float* part = (float*)(smem + PART_OFF);       // [16 waves][512] f32 partials

    const int i0 = blockIdx.x * 16;
    const int h  = blockIdx.y;
    const int b  = blockIdx.z;
    const int tid = threadIdx.x;
    const int w = tid >> 6, l = tid & 63;
    const int lr = l & 15, lk = l >> 4;            // fragment row/col, k-block

    const unsigned short* qp = qws + ((b * HDIM + h) * SDIM) * DK;
    const unsigned short* kp = kws + ((b * HDIM + h) * SDIM) * DK;
    const unsigned short* vp = vtws + ((b * HDIM + h) * DK) * SDIM;

    // ---- Phase 1: scores.  Wave w computes keys [w*128, (w+1)*128). ----
    {
        bf16x8 af = *(const bf16x8*)(qp + (i0 + lr) * DK + lk * 8);
        f32x4 dzero = {0.f, 0.f, 0.f, 0.f};
        #pragma unroll
        for (int t = 0; t < 8; ++t) {
            int j0 = w * 128 + t * 16;
            bf16x8 bfr = *(const bf16x8*)(kp + (j0 + lr) * DK + lk * 8);
            f32x4 d = __builtin_amdgcn_mfma_f32_16x16x32_bf16(af, bfr, dzero, 0, 0, 0);
            #pragma unroll
            for (int q = 0; q < 4; ++q)
                sc[(lk * 4 + q) * SDIM + j0 + lr] = d[q];
        }
    }
    __syncthreads();

    // ---- Phase 2: sparsemax, wave w owns row w. z in registers. ----
    float z[32];
    #pragma unroll
    for (int u = 0; u < 16; ++u) {
        float2 v2 = *(const float2*)&sc[w * SDIM + 2 * l + 128 * u];
        z[2 * u] = v2.x;
        z[2 * u + 1] = v2.y;
    }
    __syncthreads();   // all score reads done -> sc region reusable for P

    // row max (warm start: tau >= max - 1 always for sparsemax)
    float mx = z[0];
    #pragma unroll
    for (int e = 1; e < 32; ++e) mx = fmaxf(mx, z[e]);
    #pragma unroll
    for (int mk = 1; mk < 64; mk <<= 1) mx = fmaxf(mx, __shfl_xor(mx, mk, 64));

    float tau = mx - 1.0f;
    float cnt = -1.f;
    for (int it = 0; it < 64; ++it) {
        float ps = 0.f, pc = 0.f;
        #pragma unroll
        for (int e = 0; e < 32; ++e) {
            if (z[e] > tau) { ps += z[e]; pc += 1.f; }
        }
        #pragma unroll
        for (int mk = 1; mk < 64; mk <<= 1) {
            ps += __shfl_xor(ps, mk, 64);
            pc += __shfl_xor(pc, mk, 64);
        }
        float ntau = (ps - 1.f) / pc;   // pc >= 1 always (max stays active)
        if (pc == cnt) { tau = ntau; break; }
        cnt = pc;
        tau = ntau;
    }

    // P = max(z - tau, 0) -> bf16 pairs into pl[w][j], j = 2l + 128u {+1}
    #pragma unroll
    for (int u = 0; u < 16; ++u) {
        float p0 = z[2 * u] - tau;     p0 = p0 > 0.f ? p0 : 0.f;
        float p1 = z[2 * u + 1] - tau; p1 = p1 > 0.f ? p1 : 0.f;
        unsigned int packed = (unsigned int)f2bf(p0) | ((unsigned int)f2bf(p1) << 16);
        *(unsigned int*)&pl[w * PSTR + 2 * l + 128 * u] = packed;
    }
    __syncthreads();

    // ---- Phase 3: PV partials over this wave's keys [w*128, w*128+128) ----
    f32x4 acc0 = {0.f, 0.f, 0.f, 0.f};
    f32x4 acc1 = {0.f, 0.f, 0.f, 0.f};
    #pragma unroll
    for (int ks = 0; ks < 4; ++ks) {
        int kk = w * 128 + ks * 32;
        bf16x8 paf = *(const bf16x8*)&pl[lr * PSTR + kk + lk * 8];
        bf16x8 v0 = *(const bf16x8*)(vp + lr * SDIM + kk + lk * 8);
        bf16x8 v1 = *(const bf16x8*)(vp + (16 + lr) * SDIM + kk + lk * 8);
        acc0 = __builtin_amdgcn_mfma_f32_16x16x32_bf16(paf, v0, acc0, 0, 0, 0);
        acc1 = __builtin_amdgcn_mfma_f32_16x16x32_bf16(paf, v1, acc1, 0, 0, 0);
    }
    #pragma unroll
    for (int q = 0; q < 4; ++q) {
        part[w * 512 + (lk * 4 + q) * 32 + lr]      = acc0[q];
        part[w * 512 + (lk * 4 + q) * 32 + 16 + lr] = acc1[q];
    }
    __syncthreads();

    // ---- Phase 4: reduce the 16 wave-partials, write row w of output (f32) ----
    {
        int d = l & 31, half = l >> 5;
        float s = 0.f;
        #pragma unroll
        for (int p = 0; p < 8; ++p)
            s += part[(half * 8 + p) * 512 + w * 32 + d];
        s += __shfl_xor(s, 32, 64);
        if (l < 32)
            out[(b * SDIM + i0 + w) * DMODEL + h * DK + d] = s;
    }
}

extern "C" void kernel_launch(void* const* d_in, const int* in_sizes, int n_in,
                              void* d_out, int out_size, void* d_ws, size_t ws_size,
                              hipStream_t stream) {
    const float* query = (const float*)d_in[0];
    const float* key   = (const float*)d_in[1];
    const float* value = (const float*)d_in[2];
    const float* Wq = (const float*)d_in[3];
    const float* bq = (const float*)d_in[4];
    const float* Wk = (const float*)d_in[5];
    const float* bk = (const float*)d_in[6];
    const float* Wv = (const float*)d_in[7];
    const float* bv = (const float*)d_in[8];

    const int per = BDIM * HDIM * SDIM * DK;       // 1,048,576 elems
    unsigned short* qws  = (unsigned short*)d_ws;
    unsigned short* kws  = qws + per;
    unsigned short* vtws = kws + per;
    unsigned short* whi  = vtws + per;             // 3*65536 bf16
    unsigned short* wlo  = whi + 3 * 65536;

    convw_kernel<<<dim3(32, 3), 256, 0, stream>>>(Wq, Wk, Wv, whi, wlo);

    projmm_kernel<<<dim3(BDIM * SDIM / 16, 3), 256, 0, stream>>>(
        query, key, value, bq, bk, bv, whi, wlo, qws, kws, vtws);

    (void)hipFuncSetAttribute((const void*)attn_kernel,
                              hipFuncAttributeMaxDynamicSharedMemorySize, 131072);
    attn_kernel<<<dim3(SDIM / 16, HDIM, BDIM), 1024, 131072, stream>>>(
        qws, kws, vtws, (float*)d_out);
}

// Round 13
// 184.987 us; speedup vs baseline: 1.4675x; 1.1790x over previous
//
#include <hip/hip_runtime.h>
#include <hip/hip_bf16.h>

#define BDIM 2
#define SDIM 2048
#define HDIM 8
#define DK 32
#define DMODEL 256
#define SCALE_Q 0.17677669529663687f  // 1/sqrt(32)

typedef __attribute__((ext_vector_type(8))) short bf16x8;
typedef __attribute__((ext_vector_type(4))) float f32x4;

__device__ __forceinline__ float bf2f(unsigned short u) {
    union { unsigned int i; float f; } c;
    c.i = ((unsigned int)u) << 16;
    return c.f;
}
__device__ __forceinline__ unsigned short f2bf(float f) {
    union { float f; unsigned int i; } c;
    c.f = f;
    unsigned int u = c.i;
    return (unsigned short)((u + 0x7FFFu + ((u >> 16) & 1u)) >> 16);
}
// pack two f32 -> f16x2 word (RTN via scalar casts; 1 v_cvt each + pack)
__device__ __forceinline__ unsigned int pk_f16(float a, float b) {
    union { _Float16 h; unsigned short u; } ca, cb;
    ca.h = (_Float16)a; cb.h = (_Float16)b;
    return (unsigned int)ca.u | ((unsigned int)cb.u << 16);
}
__device__ __forceinline__ float up_f16(unsigned int w, int sh) {
    union { unsigned short u; _Float16 h; } c;
    c.u = (unsigned short)(w >> sh);
    return (float)c.h;
}
// pack two f32 -> bf16x2 word, single instruction
__device__ __forceinline__ unsigned int pk_bf16(float a, float b) {
    unsigned int r;
    asm volatile("v_cvt_pk_bf16_f32 %0, %1, %2" : "=v"(r) : "v"(a), "v"(b));
    return r;
}

// ---------------------------------------------------------------------------
// Kernel 0: split W (f32) -> Whi + Wlo bf16 pairs. 3 x 256x256 mats.
// ---------------------------------------------------------------------------
__global__ __launch_bounds__(256) void convw_kernel(
    const float* __restrict__ Wq, const float* __restrict__ Wk,
    const float* __restrict__ Wv,
    unsigned short* __restrict__ whi, unsigned short* __restrict__ wlo)
{
    const int m = blockIdx.y;
    const float* W = (m == 0) ? Wq : (m == 1) ? Wk : Wv;
    const int i = blockIdx.x * 2048 + threadIdx.x * 8;
    float4 a = *(const float4*)(W + i);
    float4 b = *(const float4*)(W + i + 4);
    float v[8] = {a.x, a.y, a.z, a.w, b.x, b.y, b.z, b.w};
    bf16x8 h8, l8;
    #pragma unroll
    for (int e = 0; e < 8; ++e) {
        unsigned short h = f2bf(v[e]);
        h8[e] = (short)h;
        l8[e] = (short)f2bf(v[e] - bf2f(h));
    }
    *(bf16x8*)(whi + m * 65536 + i) = h8;
    *(bf16x8*)(wlo + m * 65536 + i) = l8;
}

// ---------------------------------------------------------------------------
// Kernel 1: MFMA projections with split-bf16 (err ~2^-17, ~= f32 accuracy).
// y = Whi*Xhi + Whi*Xlo + Wlo*Xhi  (lo*lo dropped).
// ---------------------------------------------------------------------------
__global__ __launch_bounds__(256) void projmm_kernel(
    const float* __restrict__ query, const float* __restrict__ key,
    const float* __restrict__ value,
    const float* __restrict__ bq, const float* __restrict__ bk,
    const float* __restrict__ bv,
    const unsigned short* __restrict__ whi, const unsigned short* __restrict__ wlo,
    unsigned short* __restrict__ qws, unsigned short* __restrict__ kws,
    unsigned short* __restrict__ vtws)
{
    const int m = blockIdx.y;
    const float* x    = (m == 0) ? query : (m == 1) ? key : value;
    const float* bias = (m == 0) ? bq : (m == 1) ? bk : bv;
    const unsigned short* wh = whi + m * 65536;
    const unsigned short* wl = wlo + m * 65536;

    const int t0 = blockIdx.x * 16;
    const int tid = threadIdx.x;
    const int w = tid >> 6, l = tid & 63;
    const int lr = l & 15, lk = l >> 4;
    const int o0 = w * 64;

    f32x4 acc[4];
    #pragma unroll
    for (int nt = 0; nt < 4; ++nt) acc[nt] = (f32x4){0.f, 0.f, 0.f, 0.f};

    const float* xrow = x + (t0 + lr) * DMODEL;
    #pragma unroll
    for (int c = 0; c < 8; ++c) {
        const int kk = c * 32 + lk * 8;
        float4 xa = *(const float4*)(xrow + kk);
        float4 xb = *(const float4*)(xrow + kk + 4);
        float xv[8] = {xa.x, xa.y, xa.z, xa.w, xb.x, xb.y, xb.z, xb.w};
        bf16x8 xhi, xlo;
        #pragma unroll
        for (int e = 0; e < 8; ++e) {
            unsigned short h = f2bf(xv[e]);
            xhi[e] = (short)h;
            xlo[e] = (short)f2bf(xv[e] - bf2f(h));
        }
        #pragma unroll
        for (int nt = 0; nt < 4; ++nt) {
            bf16x8 ahi = *(const bf16x8*)(wh + (o0 + nt * 16 + lr) * DMODEL + kk);
            bf16x8 alo = *(const bf16x8*)(wl + (o0 + nt * 16 + lr) * DMODEL + kk);
            acc[nt] = __builtin_amdgcn_mfma_f32_16x16x32_bf16(ahi, xhi, acc[nt], 0, 0, 0);
            acc[nt] = __builtin_amdgcn_mfma_f32_16x16x32_bf16(ahi, xlo, acc[nt], 0, 0, 0);
            acc[nt] = __builtin_amdgcn_mfma_f32_16x16x32_bf16(alo, xhi, acc[nt], 0, 0, 0);
        }
    }

    const int token = t0 + lr;
    const int b = token >> 11, s = token & 2047;
    #pragma unroll
    for (int nt = 0; nt < 4; ++nt) {
        #pragma unroll
        for (int q = 0; q < 4; ++q) {
            const int o = o0 + nt * 16 + lk * 4 + q;
            const float y = acc[nt][q] + bias[o];
            const int h = o >> 5, dk = o & 31;
            if (m == 0)
                qws[(((b * HDIM + h) * SDIM + s) << 5) + dk] = f2bf(y * SCALE_Q);
            else if (m == 1)
                kws[(((b * HDIM + h) * SDIM + s) << 5) + dk] = f2bf(y);
            else
                vtws[(((b * HDIM + h) * DK + dk) << 11) + s] = f2bf(y);
        }
    }
}

// ---------------------------------------------------------------------------
// Kernel 2: 80 KiB LDS (2 blocks/CU).  Layout (all XOR-swizzled, no pads):
//   [0,64K):  scores as f16x2 words [8 rowpairs][2048 keys]   (phases 1-2)
//             then P bf16 [16 rows][2048 keys]                (phases 2-3)
//   [64K,80K): partials f16x2 [16 waves][8 rowpairs][32 dcol] (phases 3-4)
// Swizzles: score word idx ^= (rp&7)<<2 ; P u16 idx ^= (row&7)<<3 ;
//           partial word idx ^= (rp&7)<<2.
// ---------------------------------------------------------------------------
__global__ __launch_bounds__(1024) void attn_kernel(
    const unsigned short* __restrict__ qws,
    const unsigned short* __restrict__ kws,
    const unsigned short* __restrict__ vtws,
    float* __restrict__ out)
{
    extern __shared__ char smem[];
    unsigned int* scw  = (unsigned int*)smem;            // [8][2048] f16x2
    unsigned short* pl = (unsigned short*)smem;          // [16][2048] bf16 (overlaps)
    unsigned int* part = (unsigned int*)(smem + 65536);  // [16][256] f16x2

    const int i0 = blockIdx.x * 16;
    const int h  = blockIdx.y;
    const int b  = blockIdx.z;
    const int tid = threadIdx.x;
    const int w = tid >> 6, l = tid & 63;
    const int lr = l & 15, lk = l >> 4;

    const unsigned short* qp = qws + ((b * HDIM + h) * SDIM) * DK;
    const unsigned short* kp = kws + ((b * HDIM + h) * SDIM) * DK;
    const unsigned short* vp = vtws + ((b * HDIM + h) * DK) * SDIM;

    // ---- Phase 1: scores -> f16 pairs.  Wave w: keys [w*128, (w+1)*128). ----
    {
        bf16x8 af = *(const bf16x8*)(qp + (i0 + lr) * DK + lk * 8);
        f32x4 dzero = {0.f, 0.f, 0.f, 0.f};
        const int rp0 = 2 * lk, rp1 = 2 * lk + 1;
        #pragma unroll
        for (int t = 0; t < 8; ++t) {
            int j = w * 128 + t * 16 + lr;
            bf16x8 bfr = *(const bf16x8*)(kp + (w * 128 + t * 16 + lr) * DK + lk * 8);
            f32x4 d = __builtin_amdgcn_mfma_f32_16x16x32_bf16(af, bfr, dzero, 0, 0, 0);
            scw[(rp0 * 2048 + j) ^ ((rp0 & 7) << 2)] = pk_f16(d[0], d[1]); // rows 4lk,4lk+1
            scw[(rp1 * 2048 + j) ^ ((rp1 & 7) << 2)] = pk_f16(d[2], d[3]); // rows 4lk+2,4lk+3
        }
    }
    __syncthreads();

    // ---- Phase 2: sparsemax, wave w owns row w. ----
    float z[32];
    {
        const int rp = w >> 1, sh = (w & 1) << 4;
        const int zb = rp * 2048, zs = (rp & 7) << 2;
        #pragma unroll
        for (int u = 0; u < 16; ++u) {
            uint2 rd = *(const uint2*)&scw[(zb + 2 * l + 128 * u) ^ zs];
            z[2 * u]     = up_f16(rd.x, sh);
            z[2 * u + 1] = up_f16(rd.y, sh);
        }
    }
    __syncthreads();   // all score reads done -> region reusable for P

    float mx = z[0];
    #pragma unroll
    for (int e = 1; e < 32; ++e) mx = fmaxf(mx, z[e]);
    #pragma unroll
    for (int mk = 1; mk < 64; mk <<= 1) mx = fmaxf(mx, __shfl_xor(mx, mk, 64));

    float tau = mx - 1.0f;     // sparsemax guarantees tau >= max-1
    float cnt = -1.f;
    for (int it = 0; it < 64; ++it) {
        float ps = 0.f, pc = 0.f;
        #pragma unroll
        for (int e = 0; e < 32; ++e) {
            if (z[e] > tau) { ps += z[e]; pc += 1.f; }
        }
        #pragma unroll
        for (int mk = 1; mk < 64; mk <<= 1) {
            ps += __shfl_xor(ps, mk, 64);
            pc += __shfl_xor(pc, mk, 64);
        }
        float ntau = (ps - 1.f) / pc;
        if (pc == cnt) { tau = ntau; break; }
        cnt = pc;
        tau = ntau;
    }

    // P = max(z-tau,0) -> bf16 pairs; u32 idx = w*1024 + l + 64u, ^ (w&7)<<2
    {
        unsigned int* plw = (unsigned int*)pl;
        const int ps_ = (w & 7) << 2;
        #pragma unroll
        for (int u = 0; u < 16; ++u) {
            float p0 = z[2 * u] - tau;     p0 = p0 > 0.f ? p0 : 0.f;
            float p1 = z[2 * u + 1] - tau; p1 = p1 > 0.f ? p1 : 0.f;
            plw[(w * 1024 + l + 64 * u) ^ ps_] = pk_bf16(p0, p1);
        }
    }
    __syncthreads();

    // ---- Phase 3: PV partials over wave's keys [w*128, w*128+128) ----
    f32x4 acc0 = {0.f, 0.f, 0.f, 0.f};
    f32x4 acc1 = {0.f, 0.f, 0.f, 0.f};
    #pragma unroll
    for (int ks = 0; ks < 4; ++ks) {
        int kk = w * 128 + ks * 32;
        bf16x8 paf = *(const bf16x8*)&pl[(lr * 2048 + kk + lk * 8) ^ ((lr & 7) << 3)];
        bf16x8 v0 = *(const bf16x8*)(vp + lr * SDIM + kk + lk * 8);
        bf16x8 v1 = *(const bf16x8*)(vp + (16 + lr) * SDIM + kk + lk * 8);
        acc0 = __builtin_amdgcn_mfma_f32_16x16x32_bf16(paf, v0, acc0, 0, 0, 0);
        acc1 = __builtin_amdgcn_mfma_f32_16x16x32_bf16(paf, v1, acc1, 0, 0, 0);
    }
    // partials: word (w, rp=2lk+p, dcol) packs rows (2rp, 2rp+1)
    #pragma unroll
    for (int p = 0; p < 2; ++p) {
        const int rpp = 2 * lk + p, sw = (rpp & 7) << 2;
        part[(w * 256 + rpp * 32 + lr)      ^ sw] = pk_f16(acc0[2 * p], acc0[2 * p + 1]);
        part[(w * 256 + rpp * 32 + 16 + lr) ^ sw] = pk_f16(acc1[2 * p], acc1[2 * p + 1]);
    }
    __syncthreads();

    // ---- Phase 4: reduce 16 wave-partials for output row w, write f32 ----
    {
        const int d = l & 31, half = l >> 5;
        const int rp = w >> 1, sh = (w & 1) << 4, sw = (rp & 7) << 2;
        float s = 0.f;
        #pragma unroll
        for (int p = 0; p < 8; ++p)
            s += up_f16(part[((half * 8 + p) * 256 + rp * 32 + d) ^ sw], sh);
        s += __shfl_xor(s, 32, 64);
        if (l < 32)
            out[(b * SDIM + i0 + w) * DMODEL + h * DK + d] = s;
    }
}

extern "C" void kernel_launch(void* const* d_in, const int* in_sizes, int n_in,
                              void* d_out, int out_size, void* d_ws, size_t ws_size,
                              hipStream_t stream) {
    const float* query = (const float*)d_in[0];
    const float* key   = (const float*)d_in[1];
    const float* value = (const float*)d_in[2];
    const float* Wq = (const float*)d_in[3];
    const float* bq = (const float*)d_in[4];
    const float* Wk = (const float*)d_in[5];
    const float* bk = (const float*)d_in[6];
    const float* Wv = (const float*)d_in[7];
    const float* bv = (const float*)d_in[8];

    const int per = BDIM * HDIM * SDIM * DK;       // 1,048,576 elems
    unsigned short* qws  = (unsigned short*)d_ws;
    unsigned short* kws  = qws + per;
    unsigned short* vtws = kws + per;
    unsigned short* whi  = vtws + per;             // 3*65536 bf16
    unsigned short* wlo  = whi + 3 * 65536;

    convw_kernel<<<dim3(32, 3), 256, 0, stream>>>(Wq, Wk, Wv, whi, wlo);

    projmm_kernel<<<dim3(BDIM * SDIM / 16, 3), 256, 0, stream>>>(
        query, key, value, bq, bk, bv, whi, wlo, qws, kws, vtws);

    (void)hipFuncSetAttribute((const void*)attn_kernel,
                              hipFuncAttributeMaxDynamicSharedMemorySize, 81920);
    attn_kernel<<<dim3(SDIM / 16, HDIM, BDIM), 1024, 81920, stream>>>(
        qws, kws, vtws, (float*)d_out);
}

// Round 14
// 183.519 us; speedup vs baseline: 1.4793x; 1.0080x over previous
//
#include <hip/hip_runtime.h>
#include <hip/hip_bf16.h>

#define BDIM 2
#define SDIM 2048
#define HDIM 8
#define DK 32
#define DMODEL 256
#define SCALE_Q 0.17677669529663687f  // 1/sqrt(32)

typedef __attribute__((ext_vector_type(8))) short bf16x8;
typedef __attribute__((ext_vector_type(4))) float f32x4;

__device__ __forceinline__ float bf2f(unsigned short u) {
    union { unsigned int i; float f; } c;
    c.i = ((unsigned int)u) << 16;
    return c.f;
}
__device__ __forceinline__ unsigned short f2bf(float f) {
    union { float f; unsigned int i; } c;
    c.f = f;
    unsigned int u = c.i;
    return (unsigned short)((u + 0x7FFFu + ((u >> 16) & 1u)) >> 16);
}
// pack two f32 -> f16x2 word (RTN via scalar casts; 1 v_cvt each + pack)
__device__ __forceinline__ unsigned int pk_f16(float a, float b) {
    union { _Float16 h; unsigned short u; } ca, cb;
    ca.h = (_Float16)a; cb.h = (_Float16)b;
    return (unsigned int)ca.u | ((unsigned int)cb.u << 16);
}
__device__ __forceinline__ float up_f16(unsigned int w, int sh) {
    union { unsigned short u; _Float16 h; } c;
    c.u = (unsigned short)(w >> sh);
    return (float)c.h;
}
// pack two f32 -> bf16x2 word, single instruction
__device__ __forceinline__ unsigned int pk_bf16(float a, float b) {
    unsigned int r;
    asm volatile("v_cvt_pk_bf16_f32 %0, %1, %2" : "=v"(r) : "v"(a), "v"(b));
    return r;
}

// ---------------------------------------------------------------------------
// Kernel 0: split W (f32) -> Whi + Wlo bf16 pairs. 3 x 256x256 mats.
// ---------------------------------------------------------------------------
__global__ __launch_bounds__(256) void convw_kernel(
    const float* __restrict__ Wq, const float* __restrict__ Wk,
    const float* __restrict__ Wv,
    unsigned short* __restrict__ whi, unsigned short* __restrict__ wlo)
{
    const int m = blockIdx.y;
    const float* W = (m == 0) ? Wq : (m == 1) ? Wk : Wv;
    const int i = blockIdx.x * 2048 + threadIdx.x * 8;
    float4 a = *(const float4*)(W + i);
    float4 b = *(const float4*)(W + i + 4);
    float v[8] = {a.x, a.y, a.z, a.w, b.x, b.y, b.z, b.w};
    bf16x8 h8, l8;
    #pragma unroll
    for (int e = 0; e < 8; ++e) {
        unsigned short h = f2bf(v[e]);
        h8[e] = (short)h;
        l8[e] = (short)f2bf(v[e] - bf2f(h));
    }
    *(bf16x8*)(whi + m * 65536 + i) = h8;
    *(bf16x8*)(wlo + m * 65536 + i) = l8;
}

// ---------------------------------------------------------------------------
// Kernel 1: MFMA projections with split-bf16 (err ~2^-17, ~= f32 accuracy).
// y = Whi*Xhi + Whi*Xlo + Wlo*Xhi  (lo*lo dropped).
// ---------------------------------------------------------------------------
__global__ __launch_bounds__(256) void projmm_kernel(
    const float* __restrict__ query, const float* __restrict__ key,
    const float* __restrict__ value,
    const float* __restrict__ bq, const float* __restrict__ bk,
    const float* __restrict__ bv,
    const unsigned short* __restrict__ whi, const unsigned short* __restrict__ wlo,
    unsigned short* __restrict__ qws, unsigned short* __restrict__ kws,
    unsigned short* __restrict__ vtws)
{
    const int m = blockIdx.y;
    const float* x    = (m == 0) ? query : (m == 1) ? key : value;
    const float* bias = (m == 0) ? bq : (m == 1) ? bk : bv;
    const unsigned short* wh = whi + m * 65536;
    const unsigned short* wl = wlo + m * 65536;

    const int t0 = blockIdx.x * 16;
    const int tid = threadIdx.x;
    const int w = tid >> 6, l = tid & 63;
    const int lr = l & 15, lk = l >> 4;
    const int o0 = w * 64;

    f32x4 acc[4];
    #pragma unroll
    for (int nt = 0; nt < 4; ++nt) acc[nt] = (f32x4){0.f, 0.f, 0.f, 0.f};

    const float* xrow = x + (t0 + lr) * DMODEL;
    #pragma unroll
    for (int c = 0; c < 8; ++c) {
        const int kk = c * 32 + lk * 8;
        float4 xa = *(const float4*)(xrow + kk);
        float4 xb = *(const float4*)(xrow + kk + 4);
        float xv[8] = {xa.x, xa.y, xa.z, xa.w, xb.x, xb.y, xb.z, xb.w};
        bf16x8 xhi, xlo;
        #pragma unroll
        for (int e = 0; e < 8; ++e) {
            unsigned short h = f2bf(xv[e]);
            xhi[e] = (short)h;
            xlo[e] = (short)f2bf(xv[e] - bf2f(h));
        }
        #pragma unroll
        for (int nt = 0; nt < 4; ++nt) {
            bf16x8 ahi = *(const bf16x8*)(wh + (o0 + nt * 16 + lr) * DMODEL + kk);
            bf16x8 alo = *(const bf16x8*)(wl + (o0 + nt * 16 + lr) * DMODEL + kk);
            acc[nt] = __builtin_amdgcn_mfma_f32_16x16x32_bf16(ahi, xhi, acc[nt], 0, 0, 0);
            acc[nt] = __builtin_amdgcn_mfma_f32_16x16x32_bf16(ahi, xlo, acc[nt], 0, 0, 0);
            acc[nt] = __builtin_amdgcn_mfma_f32_16x16x32_bf16(alo, xhi, acc[nt], 0, 0, 0);
        }
    }

    const int token = t0 + lr;
    const int b = token >> 11, s = token & 2047;
    #pragma unroll
    for (int nt = 0; nt < 4; ++nt) {
        #pragma unroll
        for (int q = 0; q < 4; ++q) {
            const int o = o0 + nt * 16 + lk * 4 + q;
            const float y = acc[nt][q] + bias[o];
            const int h = o >> 5, dk = o & 31;
            if (m == 0)
                qws[(((b * HDIM + h) * SDIM + s) << 5) + dk] = f2bf(y * SCALE_Q);
            else if (m == 1)
                kws[(((b * HDIM + h) * SDIM + s) << 5) + dk] = f2bf(y);
            else
                vtws[(((b * HDIM + h) * DK + dk) << 11) + s] = f2bf(y);
        }
    }
}

// ---------------------------------------------------------------------------
// Kernel 2: 80 KiB LDS (2 blocks/CU).  Layout (all XOR-swizzled, no pads):
//   [0,64K):  scores as f16x2 words [8 rowpairs][2048 keys]   (phases 1-2)
//             then P bf16 [16 rows][2048 keys]                (phases 2-3)
//   [64K,80K): partials f16x2 [16 waves][8 rowpairs][32 dcol] (phases 3-4)
// Sparsemax: candidate-slot Michelot. Support of every iterate is a subset
// of {z > rowmax-1} (tau* >= max-1, tau ascends from warm start), so the
// ~10-60 candidates/row (~0-2 per lane) are cached in 4 register slots;
// per-iteration cost drops from a 32-register scan to 4 compares. Lanes
// with >4 candidates (flat rows) fall back to the full scan, exec-masked.
// ---------------------------------------------------------------------------
__global__ __launch_bounds__(1024, 8) void attn_kernel(
    const unsigned short* __restrict__ qws,
    const unsigned short* __restrict__ kws,
    const unsigned short* __restrict__ vtws,
    float* __restrict__ out)
{
    extern __shared__ char smem[];
    unsigned int* scw  = (unsigned int*)smem;            // [8][2048] f16x2
    unsigned short* pl = (unsigned short*)smem;          // [16][2048] bf16 (overlaps)
    unsigned int* part = (unsigned int*)(smem + 65536);  // [16][256] f16x2

    const int i0 = blockIdx.x * 16;
    const int h  = blockIdx.y;
    const int b  = blockIdx.z;
    const int tid = threadIdx.x;
    const int w = tid >> 6, l = tid & 63;
    const int lr = l & 15, lk = l >> 4;

    const unsigned short* qp = qws + ((b * HDIM + h) * SDIM) * DK;
    const unsigned short* kp = kws + ((b * HDIM + h) * SDIM) * DK;
    const unsigned short* vp = vtws + ((b * HDIM + h) * DK) * SDIM;

    // ---- Phase 1: scores -> f16 pairs.  Wave w: keys [w*128, (w+1)*128). ----
    {
        bf16x8 af = *(const bf16x8*)(qp + (i0 + lr) * DK + lk * 8);
        f32x4 dzero = {0.f, 0.f, 0.f, 0.f};
        const int rp0 = 2 * lk, rp1 = 2 * lk + 1;
        #pragma unroll
        for (int t = 0; t < 8; ++t) {
            int j = w * 128 + t * 16 + lr;
            bf16x8 bfr = *(const bf16x8*)(kp + (w * 128 + t * 16 + lr) * DK + lk * 8);
            f32x4 d = __builtin_amdgcn_mfma_f32_16x16x32_bf16(af, bfr, dzero, 0, 0, 0);
            scw[(rp0 * 2048 + j) ^ ((rp0 & 7) << 2)] = pk_f16(d[0], d[1]); // rows 4lk,4lk+1
            scw[(rp1 * 2048 + j) ^ ((rp1 & 7) << 2)] = pk_f16(d[2], d[3]); // rows 4lk+2,4lk+3
        }
    }
    __syncthreads();

    // ---- Phase 2: sparsemax, wave w owns row w. ----
    float z[32];
    const int rp = w >> 1, sh = (w & 1) << 4;
    const int zb = rp * 2048, zs = (rp & 7) << 2;
    #pragma unroll
    for (int u = 0; u < 16; ++u) {
        uint2 rd = *(const uint2*)&scw[(zb + 2 * l + 128 * u) ^ zs];
        z[2 * u]     = up_f16(rd.x, sh);
        z[2 * u + 1] = up_f16(rd.y, sh);
    }

    // wave-local row max -> warm-start threshold
    float mx = z[0];
    #pragma unroll
    for (int e = 1; e < 32; ++e) mx = fmaxf(mx, z[e]);
    #pragma unroll
    for (int mk = 1; mk < 64; mk <<= 1) mx = fmaxf(mx, __shfl_xor(mx, mk, 64));
    const float thr = mx - 1.0f;

    // candidate mask over this lane's 32 elements
    unsigned int cm = 0;
    #pragma unroll
    for (int e = 0; e < 32; ++e)
        if (z[e] > thr) cm |= (1u << e);
    const int n = __popc(cm);

    // extract up to 4 candidate values (ascending element order) via LDS
    // re-read; must finish BEFORE the barrier that frees the score region.
    float c0 = -3e38f, c1 = -3e38f, c2 = -3e38f, c3 = -3e38f;
    {
        unsigned int m = cm;
        if (m) {
            int e = __builtin_ctz(m); m &= m - 1;
            c0 = up_f16(scw[((zb + 2 * l + 128 * (e >> 1)) ^ zs) + (e & 1)], sh);
            if (m) {
                e = __builtin_ctz(m); m &= m - 1;
                c1 = up_f16(scw[((zb + 2 * l + 128 * (e >> 1)) ^ zs) + (e & 1)], sh);
                if (m) {
                    e = __builtin_ctz(m); m &= m - 1;
                    c2 = up_f16(scw[((zb + 2 * l + 128 * (e >> 1)) ^ zs) + (e & 1)], sh);
                    if (m) {
                        e = __builtin_ctz(m);
                        c3 = up_f16(scw[((zb + 2 * l + 128 * (e >> 1)) ^ zs) + (e & 1)], sh);
                    }
                }
            }
        }
    }
    __syncthreads();   // all score reads done -> region reusable for P

    float tau = thr;
    float cnt = -1.f;
    for (int it = 0; it < 64; ++it) {
        float ps, pc;
        if (n <= 4) {        // common path: candidates fit the 4 slots
            ps = 0.f; pc = 0.f;
            if (c0 > tau) { ps += c0; pc += 1.f; }
            if (c1 > tau) { ps += c1; pc += 1.f; }
            if (c2 > tau) { ps += c2; pc += 1.f; }
            if (c3 > tau) { ps += c3; pc += 1.f; }
        } else {             // rare (flat row): rescan registers
            ps = 0.f; pc = 0.f;
            #pragma unroll
            for (int e = 0; e < 32; ++e)
                if (z[e] > tau) { ps += z[e]; pc += 1.f; }
        }
        #pragma unroll
        for (int mk = 1; mk < 64; mk <<= 1) {
            ps += __shfl_xor(ps, mk, 64);
            pc += __shfl_xor(pc, mk, 64);
        }
        float ntau = (ps - 1.f) / pc;
        if (pc == cnt) { tau = ntau; break; }
        cnt = pc;
        tau = ntau;
    }

    // P = max(z-tau,0) -> bf16 pairs; u32 idx = w*1024 + l + 64u, ^ (w&7)<<2
    {
        unsigned int* plw = (unsigned int*)pl;
        const int ps_ = (w & 7) << 2;
        #pragma unroll
        for (int u = 0; u < 16; ++u) {
            float p0 = z[2 * u] - tau;     p0 = p0 > 0.f ? p0 : 0.f;
            float p1 = z[2 * u + 1] - tau; p1 = p1 > 0.f ? p1 : 0.f;
            plw[(w * 1024 + l + 64 * u) ^ ps_] = pk_bf16(p0, p1);
        }
    }
    __syncthreads();

    // ---- Phase 3: PV partials over wave's keys [w*128, w*128+128) ----
    f32x4 acc0 = {0.f, 0.f, 0.f, 0.f};
    f32x4 acc1 = {0.f, 0.f, 0.f, 0.f};
    #pragma unroll
    for (int ks = 0; ks < 4; ++ks) {
        int kk = w * 128 + ks * 32;
        bf16x8 paf = *(const bf16x8*)&pl[(lr * 2048 + kk + lk * 8) ^ ((lr & 7) << 3)];
        bf16x8 v0 = *(const bf16x8*)(vp + lr * SDIM + kk + lk * 8);
        bf16x8 v1 = *(const bf16x8*)(vp + (16 + lr) * SDIM + kk + lk * 8);
        acc0 = __builtin_amdgcn_mfma_f32_16x16x32_bf16(paf, v0, acc0, 0, 0, 0);
        acc1 = __builtin_amdgcn_mfma_f32_16x16x32_bf16(paf, v1, acc1, 0, 0, 0);
    }
    // partials: word (w, rp=2lk+p, dcol) packs rows (2rp, 2rp+1)
    #pragma unroll
    for (int p = 0; p < 2; ++p) {
        const int rpp = 2 * lk + p, sw = (rpp & 7) << 2;
        part[(w * 256 + rpp * 32 + lr)      ^ sw] = pk_f16(acc0[2 * p], acc0[2 * p + 1]);
        part[(w * 256 + rpp * 32 + 16 + lr) ^ sw] = pk_f16(acc1[2 * p], acc1[2 * p + 1]);
    }
    __syncthreads();

    // ---- Phase 4: reduce 16 wave-partials for output row w, write f32 ----
    {
        const int d = l & 31, half = l >> 5;
        const int rp2 = w >> 1, sh2 = (w & 1) << 4, sw = (rp2 & 7) << 2;
        float s = 0.f;
        #pragma unroll
        for (int p = 0; p < 8; ++p)
            s += up_f16(part[((half * 8 + p) * 256 + rp2 * 32 + d) ^ sw], sh2);
        s += __shfl_xor(s, 32, 64);
        if (l < 32)
            out[(b * SDIM + i0 + w) * DMODEL + h * DK + d] = s;
    }
}

extern "C" void kernel_launch(void* const* d_in, const int* in_sizes, int n_in,
                              void* d_out, int out_size, void* d_ws, size_t ws_size,
                              hipStream_t stream) {
    const float* query = (const float*)d_in[0];
    const float* key   = (const float*)d_in[1];
    const float* value = (const float*)d_in[2];
    const float* Wq = (const float*)d_in[3];
    const float* bq = (const float*)d_in[4];
    const float* Wk = (const float*)d_in[5];
    const float* bk = (const float*)d_in[6];
    const float* Wv = (const float*)d_in[7];
    const float* bv = (const float*)d_in[8];

    const int per = BDIM * HDIM * SDIM * DK;       // 1,048,576 elems
    unsigned short* qws  = (unsigned short*)d_ws;
    unsigned short* kws  = qws + per;
    unsigned short* vtws = kws + per;
    unsigned short* whi  = vtws + per;             // 3*65536 bf16
    unsigned short* wlo  = whi + 3 * 65536;

    convw_kernel<<<dim3(32, 3), 256, 0, stream>>>(Wq, Wk, Wv, whi, wlo);

    projmm_kernel<<<dim3(BDIM * SDIM / 16, 3), 256, 0, stream>>>(
        query, key, value, bq, bk, bv, whi, wlo, qws, kws, vtws);

    (void)hipFuncSetAttribute((const void*)attn_kernel,
                              hipFuncAttributeMaxDynamicSharedMemorySize, 81920);
    attn_kernel<<<dim3(SDIM / 16, HDIM, BDIM), 1024, 81920, stream>>>(
        qws, kws, vtws, (float*)d_out);
}